// Round 17
// baseline (2763.131 us; speedup 1.0000x reference)
//
#include <hip/hip_runtime.h>
#include <cmath>

#define BB 64
#define TT 512
#define II 256
#define HH 1024
#define OO 512

typedef short bf8 __attribute__((ext_vector_type(8)));
typedef float f32x4 __attribute__((ext_vector_type(4)));
typedef unsigned long long u64;

#define MFMA(a, b, c) __builtin_amdgcn_mfma_f32_16x16x32_bf16((a), (b), (c), 0, 0, 0)

__device__ __forceinline__ unsigned short f2bf(float f) {
    unsigned u = __float_as_uint(f);
    return (unsigned short)((u + 0x7fffu + ((u >> 16) & 1u)) >> 16);
}
__device__ __forceinline__ float bf2f(unsigned short h) {
    return __uint_as_float((unsigned)h << 16);
}
__device__ __forceinline__ void split8(const float* v, bf8& hi, bf8& lo) {
#pragma unroll
    for (int j = 0; j < 8; ++j) {
        unsigned short h = f2bf(v[j]);
        float r = v[j] - bf2f(h);
        hi[j] = (short)h;
        lo[j] = (short)f2bf(r);
    }
}
__device__ __forceinline__ void ld8(float* v, const float* p) {
    *(float4*)v       = *(const float4*)p;
    *(float4*)(v + 4) = *(const float4*)(p + 4);
}
// Consumer h loads: plain cached (L2 merges redundant reads) — R12/R13 proven.
__device__ __forceinline__ bf8 load_h(const void* p) { return *(const bf8*)p; }
// Producer stores: sc1 write-through, coalesced 16B — R13 proven.
__device__ __forceinline__ void store_h16(void* p, u64 a, u64 b) {
    __hip_atomic_store((u64*)p, a, __ATOMIC_RELAXED, __HIP_MEMORY_SCOPE_AGENT);
    __hip_atomic_store((u64*)((char*)p + 8), b, __ATOMIC_RELAXED, __HIP_MEMORY_SCOPE_AGENT);
}
__device__ __forceinline__ unsigned ld_flag(const void* p) {
    return __hip_atomic_load((const unsigned*)p, __ATOMIC_RELAXED, __HIP_MEMORY_SCOPE_AGENT);
}
__device__ __forceinline__ void st_flag(void* p, unsigned v) {
    __hip_atomic_store((unsigned*)p, v, __ATOMIC_RELAXED, __HIP_MEMORY_SCOPE_AGENT);
}
__device__ __forceinline__ void acquire_fence() {
    __builtin_amdgcn_fence(__ATOMIC_ACQUIRE, "agent");
    asm volatile("" ::: "memory");
}

// h layout per (layer, slot, group) 64KB: 32 K-chunks x 64 lanes x (16B hi+16B lo).
// h[b][k]: chunk k>>5, lane (b&15)+16*((k&31)>>3), j=k&7: hi j*2, lo j*2+16.
// Chunk c is produced exactly by WG slot c (rows 32c..+31) of that layer/group.
//
// Grid 256 x 512: grp=bid&3 (16 batches), layer=(bid>>2)&1, slot=bid>>3.
// PER-WAVE GATING (new): wave w reads chunks 4w..4w+3 only, so it polls only
// flags 4w..4w+3 (lanes 0-3: h1-producer flags; L1 lanes 4-7: h2), then loads
// immediately — no WG-wide poll sync. WG stays internally lockstepped by the
// reduce/store syncs. Load-after-poll order: poll branch depends on loaded
// value (HW can't issue past it) + compiler barrier.
// Backpressure (ring overwrite): wave 0 checks ALL 64 WG flags >= t+7-LAG
// every 8 steps (conservative window); deadlock needs LAG<7, we use >=20.
// Ring: depth runtime {32,64,128,256}; fence every depth/2 (staleness proof
// R12); LAG = depth-12 so max overwrite distance LAG+8 <= depth-4.
__global__ __launch_bounds__(512, 1) void rnn_lag4(
    const float* __restrict__ x,
    const float* __restrict__ Wih0, const float* __restrict__ Whh0,
    const float* __restrict__ bih0, const float* __restrict__ bhh0,
    const float* __restrict__ Wih1, const float* __restrict__ Whh1,
    const float* __restrict__ bih1, const float* __restrict__ bhh1,
    const float* __restrict__ Wfc,  const float* __restrict__ bfc,
    float* __restrict__ out, float* __restrict__ ws,
    int sm, int fpm, int lag)
{
    // partials [8 waves][2 tiles][16][18] = 4608 fl; staging at +4608 (512 fl);
    // FC reuses [2560,4608) for Wfc rows.
    __shared__ float shmem[5120];
    char* staging = (char*)(shmem + 4608);

    const int tid  = threadIdx.x;
    const int w    = tid >> 6;
    const int lane = tid & 63;
    const int col  = lane & 15;
    const int kg   = lane >> 4;
    const int bid  = blockIdx.x;
    const int grp   = bid & 3;
    const int layer = (bid >> 2) & 1;
    const int slot  = bid >> 3;        // 0..31
    const int rb    = slot * 32;
    const int b0    = grp * 16;

    char* wsB    = (char*)ws;
    char* fA     = wsB;                // 128 x 16B (L0 flags)
    char* fB     = wsB + 2048;         // 128 x 16B (L1 flags)
    char* h1base = wsB + 4096;         // [depth slot][4 grp] 64KB
    char* h2base = h1base + (size_t)(sm + 1) * 4 * 65536;

    // ---- weight preload (VGPR) — identical R14-R16 ----
    bf8 wh[2][8], wl[2][8];
    {
        float v[8];
        if (layer == 0) {
            #pragma unroll
            for (int n = 0; n < 2; ++n) {
                ld8(v, Wih0 + (size_t)(rb + n * 16 + col) * II + (w * 32 + kg * 8));
                split8(v, wh[n][4], wl[n][4]);
                #pragma unroll
                for (int c = 0; c < 4; ++c) {
                    ld8(v, Whh0 + (size_t)(rb + n * 16 + col) * HH + ((w * 4 + c) * 32 + kg * 8));
                    split8(v, wh[n][c], wl[n][c]);
                }
            }
        } else {
            #pragma unroll
            for (int n = 0; n < 2; ++n)
                #pragma unroll
                for (int c = 0; c < 4; ++c) {
                    ld8(v, Wih1 + (size_t)(rb + n * 16 + col) * HH + ((w * 4 + c) * 32 + kg * 8));
                    split8(v, wh[n][c], wl[n][c]);
                    ld8(v, Whh1 + (size_t)(rb + n * 16 + col) * HH + ((w * 4 + c) * 32 + kg * 8));
                    split8(v, wh[n][4 + c], wl[n][4 + c]);
                }
        }
    }

    // ---- epilogue role: one thread per output element (2 tiles x 16 x 16) ----
    const int n_  = tid >> 8;
    const int ekk = (tid >> 4) & 15;
    const int eb  = tid & 15;
    const int R   = rb + n_ * 16 + ekk;
    const float bsum = layer ? (bih1[R] + bhh1[R]) : (bih0[R] + bhh0[R]);
    const int kk5 = n_ * 16 + ekk;
    const int stg = (eb + 16 * (kk5 >> 3)) * 32 + (kk5 & 7) * 2;

    acquire_fence();   // kill stale lines from a previous graph replay

    float xv[8];
    if (layer == 0)
        ld8(xv, x + (size_t)(b0 + col) * TT * II + (w * 32 + kg * 8));

    for (int t = 0; t < TT; ++t) {
        if ((t & fpm) == 0) acquire_fence();

        f32x4 acc0 = {0.f, 0.f, 0.f, 0.f};
        f32x4 acc1 = {0.f, 0.f, 0.f, 0.f};

        if (layer == 0) {
            // x-part MFMAs before the poll (no dependency on flags)
            bf8 xh, xl;
            split8(xv, xh, xl);
            acc0 = MFMA(xh, wh[0][4], acc0); acc0 = MFMA(xh, wl[0][4], acc0);
            acc0 = MFMA(xl, wh[0][4], acc0);
            acc1 = MFMA(xh, wh[1][4], acc1); acc1 = MFMA(xh, wl[1][4], acc1);
            acc1 = MFMA(xl, wh[1][4], acc1);

            // per-wave poll: lanes 0-3 gate this wave's 4 h1 chunks (fA >= t)
            {
                const char* fp = fA + (size_t)(grp * 32 + (w * 4 + (lane & 3))) * 16;
                for (;;) {
                    int f = (lane < 4) ? (int)ld_flag(fp) : 0x7fffffff;
                    if (__all(f >= t)) break;
                }
            }
            // periodic backpressure: wave 0, every 8 steps, all 64 WG flags
            if ((t & 7) == 0 && w == 0) {
                const char* fp = (lane < 32 ? fA : fB)
                               + (size_t)(grp * 32 + (lane & 31)) * 16;
                const int tgt = t + 7 - lag;
                for (;;) {
                    int f = (int)ld_flag(fp);
                    if (__all(f >= tgt)) break;
                }
            }
            asm volatile("" ::: "memory");

            if (t >= 1) {
                const char* h1r = h1base + (size_t)(((t - 1) & sm) * 4 + grp) * 65536;
                #pragma unroll
                for (int c = 0; c < 4; ++c) {
                    const char* p = h1r + (size_t)(w * 4 + c) * 2048 + lane * 32;
                    bf8 hh = load_h(p), hl = load_h(p + 16);
                    acc0 = MFMA(hh, wh[0][c], acc0); acc0 = MFMA(hh, wl[0][c], acc0);
                    acc0 = MFMA(hl, wh[0][c], acc0);
                    acc1 = MFMA(hh, wh[1][c], acc1); acc1 = MFMA(hh, wl[1][c], acc1);
                    acc1 = MFMA(hl, wh[1][c], acc1);
                }
            }
        } else {
            // per-wave poll: lanes 0-3: fA[4w+pc] >= t+1 (h1(t));
            //                lanes 4-7: fB[4w+pc] >= t   (h2(t-1))
            {
                const int pc = lane & 3;
                const char* fp = (lane < 4 ? fA : fB)
                               + (size_t)(grp * 32 + (w * 4 + pc)) * 16;
                const int tgt = (lane < 4) ? (t + 1) : t;
                for (;;) {
                    int f = (lane < 8) ? (int)ld_flag(fp) : 0x7fffffff;
                    if (__all(f >= tgt)) break;
                }
            }
            asm volatile("" ::: "memory");

            {
                const char* h1r = h1base + (size_t)((t & sm) * 4 + grp) * 65536;
                #pragma unroll
                for (int c = 0; c < 4; ++c) {
                    const char* p = h1r + (size_t)(w * 4 + c) * 2048 + lane * 32;
                    bf8 hh = load_h(p), hl = load_h(p + 16);
                    acc0 = MFMA(hh, wh[0][c], acc0); acc0 = MFMA(hh, wl[0][c], acc0);
                    acc0 = MFMA(hl, wh[0][c], acc0);
                    acc1 = MFMA(hh, wh[1][c], acc1); acc1 = MFMA(hh, wl[1][c], acc1);
                    acc1 = MFMA(hl, wh[1][c], acc1);
                }
            }
            if (t >= 1) {
                const char* h2r = h2base + (size_t)(((t - 1) & sm) * 4 + grp) * 65536;
                #pragma unroll
                for (int c = 0; c < 4; ++c) {
                    const char* p = h2r + (size_t)(w * 4 + c) * 2048 + lane * 32;
                    bf8 hh = load_h(p), hl = load_h(p + 16);
                    acc0 = MFMA(hh, wh[0][4 + c], acc0); acc0 = MFMA(hh, wl[0][4 + c], acc0);
                    acc0 = MFMA(hl, wh[0][4 + c], acc0);
                    acc1 = MFMA(hh, wh[1][4 + c], acc1); acc1 = MFMA(hh, wl[1][4 + c], acc1);
                    acc1 = MFMA(hl, wh[1][4 + c], acc1);
                }
            }
        }

        // ---- partials: stride-18 (2-way banks) ----
        #pragma unroll
        for (int r = 0; r < 4; ++r) {
            shmem[(w * 2 + 0) * 288 + (kg * 4 + r) * 18 + col] = acc0[r];
            shmem[(w * 2 + 1) * 288 + (kg * 4 + r) * 18 + col] = acc1[r];
        }
        __syncthreads();

        // ---- reduce over 8 waves + bias + tanh + split -> staging ----
        {
            float s = bsum;
            #pragma unroll
            for (int wv = 0; wv < 8; ++wv)
                s += shmem[(wv * 2 + n_) * 288 + eb * 18 + ekk];
            const float val = tanhf(s);
            const unsigned short hi = f2bf(val);
            const unsigned short lo = f2bf(val - bf2f(hi));
            *(unsigned short*)(staging + stg)      = hi;
            *(unsigned short*)(staging + stg + 16) = lo;
        }
        __syncthreads();

        // ---- coalesced 2KB chunk store (128 x 16B, sc1) ----
        {
            char* hw = (layer ? h2base : h1base)
                     + (size_t)((t & sm) * 4 + grp) * 65536 + (size_t)slot * 2048;
            if (tid < 128) {
                const char* src = staging + tid * 16;
                store_h16(hw + tid * 16, *(const u64*)src, *(const u64*)(src + 8));
            }
        }
        asm volatile("s_waitcnt vmcnt(0)" ::: "memory");
        __syncthreads();
        if (tid == 0)
            st_flag((layer ? fB : fA) + (size_t)(grp * 32 + slot) * 16, (unsigned)(t + 1));

        // ---- x prefetch for t+1 (hides under next poll) ----
        if (layer == 0 && t + 1 < TT)
            ld8(xv, x + ((size_t)(b0 + col) * TT + (t + 1)) * II + (w * 32 + kg * 8));
    }

    // ---- FC gate: all 128 L1 flags >= TT, fence, then FC ----
    if (tid < 128) {
        while ((int)ld_flag(fB + (size_t)tid * 16) < TT)
            __builtin_amdgcn_s_sleep(2);
    }
    __syncthreads();
    acquire_fence();

    // FC: block computes out[:, 2*bid .. 2*bid+1]; h2(TT-1) at slot (TT-1)&sm
    float* Wlds = shmem + 2560;
    ((float4*)Wlds)[tid] = ((const float4*)(Wfc + (size_t)(2 * bid) * HH))[tid];
    __syncthreads();

    float p0 = 0.f, p1 = 0.f;
    {
        const int gr   = lane >> 4;
        const int bsub = lane & 15;
        const char* hb = h2base + (size_t)(((TT - 1) & sm) * 4 + gr) * 65536;
        #pragma unroll 4
        for (int k8 = w * 16; k8 < w * 16 + 16; ++k8) {
            const char* p = hb + (size_t)(k8 >> 2) * 2048
                          + (size_t)(bsub + ((k8 & 3) << 4)) * 32;
            bf8 hi = load_h(p), lo = load_h(p + 16);
            const int kb = k8 * 8;
            #pragma unroll
            for (int j = 0; j < 8; ++j) {
                float f = bf2f((unsigned short)hi[j]) + bf2f((unsigned short)lo[j]);
                p0 += f * Wlds[kb + j];
                p1 += f * Wlds[1024 + kb + j];
            }
        }
    }
    __syncthreads();
    shmem[(w * 64 + lane) * 2 + 0] = p0;
    shmem[(w * 64 + lane) * 2 + 1] = p1;
    __syncthreads();
    if (w < 2) {
        float s = bfc[2 * bid + w];
        #pragma unroll
        for (int j = 0; j < 8; ++j) s += shmem[(j * 64 + lane) * 2 + w];
        out[(size_t)lane * OO + 2 * bid + w] = s;
    }
}

extern "C" void kernel_launch(void* const* d_in, const int* in_sizes, int n_in,
                              void* d_out, int out_size, void* d_ws, size_t ws_size,
                              hipStream_t stream) {
    const float* x    = (const float*)d_in[0];
    const float* Wih0 = (const float*)d_in[1];
    const float* Whh0 = (const float*)d_in[2];
    const float* bih0 = (const float*)d_in[3];
    const float* bhh0 = (const float*)d_in[4];
    const float* Wih1 = (const float*)d_in[5];
    const float* Whh1 = (const float*)d_in[6];
    const float* bih1 = (const float*)d_in[7];
    const float* bhh1 = (const float*)d_in[8];
    const float* Wfc  = (const float*)d_in[9];
    const float* bfc  = (const float*)d_in[10];
    float* out = (float*)d_out;
    float* ws  = (float*)d_ws;

    // Ring depth from ws_size (never assume workspace — R1 lesson):
    // depth d needs 4KB + 2*d*4*64KB. 256 -> 134.2MB, 128 -> 67.1MB,
    // 64 -> 33.6MB (proven R15).
    int depth = 32;
    if (ws_size >= (size_t)4096 + (size_t)2 * 256 * 4 * 65536)      depth = 256;
    else if (ws_size >= (size_t)4096 + (size_t)2 * 128 * 4 * 65536) depth = 128;
    else if (ws_size >= (size_t)4096 + (size_t)2 * 64 * 4 * 65536)  depth = 64;
    int sm  = depth - 1;
    int fpm = depth / 2 - 1;
    int lag = depth - 12;   // >= 20; deadlock needs lag < 7; overwrite dist <= lag+8 <= depth-4

    // zero both flag arrays every call (replay-safe)
    hipMemsetAsync(d_ws, 0, 4096, stream);

    void* args[] = { (void*)&x,
                     (void*)&Wih0, (void*)&Whh0, (void*)&bih0, (void*)&bhh0,
                     (void*)&Wih1, (void*)&Whh1, (void*)&bih1, (void*)&bhh1,
                     (void*)&Wfc,  (void*)&bfc,  (void*)&out,  (void*)&ws,
                     (void*)&sm,   (void*)&fpm,  (void*)&lag };
    hipLaunchCooperativeKernel((void*)rnn_lag4, dim3(256), dim3(512),
                               args, 0, stream);
}

// Round 18
// 2274.238 us; speedup vs baseline: 1.2150x; 1.2150x over previous
//
#include <hip/hip_runtime.h>
#include <cmath>

#define BB 64
#define TT 512
#define II 256
#define HH 1024
#define OO 512

typedef short bf8 __attribute__((ext_vector_type(8)));
typedef float f32x4 __attribute__((ext_vector_type(4)));
typedef unsigned long long u64;

#define MFMA(a, b, c) __builtin_amdgcn_mfma_f32_16x16x32_bf16((a), (b), (c), 0, 0, 0)

__device__ __forceinline__ unsigned short f2bf(float f) {
    unsigned u = __float_as_uint(f);
    return (unsigned short)((u + 0x7fffu + ((u >> 16) & 1u)) >> 16);
}
__device__ __forceinline__ float bf2f(unsigned short h) {
    return __uint_as_float((unsigned)h << 16);
}
__device__ __forceinline__ void split8(const float* v, bf8& hi, bf8& lo) {
#pragma unroll
    for (int j = 0; j < 8; ++j) {
        unsigned short h = f2bf(v[j]);
        float r = v[j] - bf2f(h);
        hi[j] = (short)h;
        lo[j] = (short)f2bf(r);
    }
}
__device__ __forceinline__ void ld8(float* v, const float* p) {
    *(float4*)v       = *(const float4*)p;
    *(float4*)(v + 4) = *(const float4*)(p + 4);
}
// Consumer h loads: plain cached (L2 merges redundant reads) — R12/R13 proven.
__device__ __forceinline__ bf8 load_h(const void* p) { return *(const bf8*)p; }
// Producer stores: sc1 write-through, coalesced 16B — R13 proven.
__device__ __forceinline__ void store_h16(void* p, u64 a, u64 b) {
    __hip_atomic_store((u64*)p, a, __ATOMIC_RELAXED, __HIP_MEMORY_SCOPE_AGENT);
    __hip_atomic_store((u64*)((char*)p + 8), b, __ATOMIC_RELAXED, __HIP_MEMORY_SCOPE_AGENT);
}
__device__ __forceinline__ unsigned ld_flag(const void* p) {
    return __hip_atomic_load((const unsigned*)p, __ATOMIC_RELAXED, __HIP_MEMORY_SCOPE_AGENT);
}
__device__ __forceinline__ void st_flag(void* p, unsigned v) {
    __hip_atomic_store((unsigned*)p, v, __ATOMIC_RELAXED, __HIP_MEMORY_SCOPE_AGENT);
}
__device__ __forceinline__ void acquire_fence() {
    __builtin_amdgcn_fence(__ATOMIC_ACQUIRE, "agent");
    asm volatile("" ::: "memory");
}

// h layout per (layer, slot, group) 64KB: 32 K-chunks x 64 lanes x (16B hi+16B lo).
// h[b][k]: chunk k>>5, lane (b&15)+16*((k&31)>>3), j=k&7: hi j*2, lo j*2+16.
//
// R16 structure (BEST, 2.29ms): grp=bid&3 (16 batches), layer=(bid>>2)&1,
// slot=bid>>3 (rows slot*32..+31). 8 waves K-split. WAVE-0-ONLY polling
// (R17 proved 8-wave polling regresses: 8x poll streams slow flag visibility).
// L0 step t: h1(t); wave0 polls fA>=t (peers); backpressure fB >= t+7-lag
//   checked only every 8 steps (R17's one good piece; overwrite-ahead <=
//   lag+8 = depth-4, ring-safe; deadlock needs lag<7, we use >=20).
// L1 step t: h2(t); SPLIT polls: fA>=t+1 (h1(t), L0 ahead -> cheap), Wih1
//   MFMAs, then fB>=t (peers), Whh1 MFMAs.
// Ring depth runtime {32,64,128}; fence every depth/2 (staleness: >=2 own
// fences between re-reads of any address — R12 proof).
__global__ __launch_bounds__(512, 1) void rnn_lag5(
    const float* __restrict__ x,
    const float* __restrict__ Wih0, const float* __restrict__ Whh0,
    const float* __restrict__ bih0, const float* __restrict__ bhh0,
    const float* __restrict__ Wih1, const float* __restrict__ Whh1,
    const float* __restrict__ bih1, const float* __restrict__ bhh1,
    const float* __restrict__ Wfc,  const float* __restrict__ bfc,
    float* __restrict__ out, float* __restrict__ ws,
    int sm, int fpm, int lag)
{
    // partials [8 waves][2 tiles][16][18] = 4608 fl (stride 18: 2-way banks, free)
    // staging at +4608 (512 fl). FC reuses [2560,4608) for Wfc rows.
    __shared__ float shmem[5120];
    char* staging = (char*)(shmem + 4608);

    const int tid  = threadIdx.x;
    const int w    = tid >> 6;
    const int lane = tid & 63;
    const int col  = lane & 15;
    const int kg   = lane >> 4;
    const int bid  = blockIdx.x;
    const int grp   = bid & 3;
    const int layer = (bid >> 2) & 1;
    const int slot  = bid >> 3;        // 0..31
    const int rb    = slot * 32;
    const int b0    = grp * 16;

    char* wsB    = (char*)ws;
    char* fA     = wsB;                // 128 x 16B (L0 flags)
    char* fB     = wsB + 2048;         // 128 x 16B (L1 flags)
    char* h1base = wsB + 4096;         // [depth slot][4 grp] 64KB
    char* h2base = h1base + (size_t)(sm + 1) * 4 * 65536;

    // ---- weight preload (VGPR) — identical R14-R16 ----
    bf8 wh[2][8], wl[2][8];
    {
        float v[8];
        if (layer == 0) {
            #pragma unroll
            for (int n = 0; n < 2; ++n) {
                ld8(v, Wih0 + (size_t)(rb + n * 16 + col) * II + (w * 32 + kg * 8));
                split8(v, wh[n][4], wl[n][4]);
                #pragma unroll
                for (int c = 0; c < 4; ++c) {
                    ld8(v, Whh0 + (size_t)(rb + n * 16 + col) * HH + ((w * 4 + c) * 32 + kg * 8));
                    split8(v, wh[n][c], wl[n][c]);
                }
            }
        } else {
            #pragma unroll
            for (int n = 0; n < 2; ++n)
                #pragma unroll
                for (int c = 0; c < 4; ++c) {
                    ld8(v, Wih1 + (size_t)(rb + n * 16 + col) * HH + ((w * 4 + c) * 32 + kg * 8));
                    split8(v, wh[n][c], wl[n][c]);
                    ld8(v, Whh1 + (size_t)(rb + n * 16 + col) * HH + ((w * 4 + c) * 32 + kg * 8));
                    split8(v, wh[n][4 + c], wl[n][4 + c]);
                }
        }
    }

    // ---- epilogue role: one thread per output element (2 tiles x 16 x 16) ----
    const int n_  = tid >> 8;
    const int ekk = (tid >> 4) & 15;
    const int eb  = tid & 15;
    const int R   = rb + n_ * 16 + ekk;
    const float bsum = layer ? (bih1[R] + bhh1[R]) : (bih0[R] + bhh0[R]);
    const int kk5 = n_ * 16 + ekk;
    const int stg = (eb + 16 * (kk5 >> 3)) * 32 + (kk5 & 7) * 2;

    acquire_fence();   // kill stale lines from a previous graph replay

    float xv[8];
    if (layer == 0)
        ld8(xv, x + (size_t)(b0 + col) * TT * II + (w * 32 + kg * 8));

    for (int t = 0; t < TT; ++t) {
        if ((t & fpm) == 0) acquire_fence();

        f32x4 acc0 = {0.f, 0.f, 0.f, 0.f};
        f32x4 acc1 = {0.f, 0.f, 0.f, 0.f};

        if (layer == 0) {
            // x-part MFMAs before the poll (no dependency on flags)
            bf8 xh, xl;
            split8(xv, xh, xl);
            acc0 = MFMA(xh, wh[0][4], acc0); acc0 = MFMA(xh, wl[0][4], acc0);
            acc0 = MFMA(xl, wh[0][4], acc0);
            acc1 = MFMA(xh, wh[1][4], acc1); acc1 = MFMA(xh, wl[1][4], acc1);
            acc1 = MFMA(xl, wh[1][4], acc1);

            // poll (wave 0): fA>=t peers; backpressure only every 8 steps
            if (w == 0) {
                {
                    const char* fp = fA + (size_t)(grp * 32 + (lane & 31)) * 16;
                    const int tgt = t;
                    for (;;) {
                        int f = (lane < 32) ? (int)ld_flag(fp) : tgt;
                        if (__all(f >= tgt)) break;
                    }
                }
                if ((t & 7) == 0) {
                    const char* fp = fB + (size_t)(grp * 32 + (lane & 31)) * 16;
                    const int tgt = t + 7 - lag;
                    for (;;) {
                        int f = (lane < 32) ? (int)ld_flag(fp) : tgt;
                        if (__all(f >= tgt)) break;
                    }
                }
            }
            __syncthreads();

            if (t >= 1) {
                const char* h1r = h1base + (size_t)(((t - 1) & sm) * 4 + grp) * 65536;
                #pragma unroll
                for (int c = 0; c < 4; ++c) {
                    const char* p = h1r + (size_t)(w * 4 + c) * 2048 + lane * 32;
                    bf8 hh = load_h(p), hl = load_h(p + 16);
                    acc0 = MFMA(hh, wh[0][c], acc0); acc0 = MFMA(hh, wl[0][c], acc0);
                    acc0 = MFMA(hl, wh[0][c], acc0);
                    acc1 = MFMA(hh, wh[1][c], acc1); acc1 = MFMA(hh, wl[1][c], acc1);
                    acc1 = MFMA(hl, wh[1][c], acc1);
                }
            }
        } else {
            // ---- phase 1: poll fA>=t+1 (h1(t); L0 runs ahead -> usually free) ----
            if (w == 0) {
                const char* fp = fA + (size_t)(grp * 32 + (lane & 31)) * 16;
                const int tgt = t + 1;
                for (;;) {
                    int f = (lane < 32) ? (int)ld_flag(fp) : tgt;
                    if (__all(f >= tgt)) break;
                }
            }
            __syncthreads();
            {
                const char* h1r = h1base + (size_t)((t & sm) * 4 + grp) * 65536;
                #pragma unroll
                for (int c = 0; c < 4; ++c) {
                    const char* p = h1r + (size_t)(w * 4 + c) * 2048 + lane * 32;
                    bf8 hh = load_h(p), hl = load_h(p + 16);
                    acc0 = MFMA(hh, wh[0][c], acc0); acc0 = MFMA(hh, wl[0][c], acc0);
                    acc0 = MFMA(hl, wh[0][c], acc0);
                    acc1 = MFMA(hh, wh[1][c], acc1); acc1 = MFMA(hh, wl[1][c], acc1);
                    acc1 = MFMA(hl, wh[1][c], acc1);
                }
            }
            // ---- phase 2: poll fB>=t (h2(t-1) peers), then Whh1 part ----
            if (t >= 1) {
                if (w == 0) {
                    const char* fp = fB + (size_t)(grp * 32 + (lane & 31)) * 16;
                    const int tgt = t;
                    for (;;) {
                        int f = (lane < 32) ? (int)ld_flag(fp) : tgt;
                        if (__all(f >= tgt)) break;
                    }
                }
                __syncthreads();
                const char* h2r = h2base + (size_t)(((t - 1) & sm) * 4 + grp) * 65536;
                #pragma unroll
                for (int c = 0; c < 4; ++c) {
                    const char* p = h2r + (size_t)(w * 4 + c) * 2048 + lane * 32;
                    bf8 hh = load_h(p), hl = load_h(p + 16);
                    acc0 = MFMA(hh, wh[0][4 + c], acc0); acc0 = MFMA(hh, wl[0][4 + c], acc0);
                    acc0 = MFMA(hl, wh[0][4 + c], acc0);
                    acc1 = MFMA(hh, wh[1][4 + c], acc1); acc1 = MFMA(hh, wl[1][4 + c], acc1);
                    acc1 = MFMA(hl, wh[1][4 + c], acc1);
                }
            }
        }

        // ---- partials: stride-18 (2-way banks) ----
        #pragma unroll
        for (int r = 0; r < 4; ++r) {
            shmem[(w * 2 + 0) * 288 + (kg * 4 + r) * 18 + col] = acc0[r];
            shmem[(w * 2 + 1) * 288 + (kg * 4 + r) * 18 + col] = acc1[r];
        }
        __syncthreads();

        // ---- reduce over 8 waves + bias + tanh + split -> staging ----
        {
            float s = bsum;
            #pragma unroll
            for (int wv = 0; wv < 8; ++wv)
                s += shmem[(wv * 2 + n_) * 288 + eb * 18 + ekk];
            const float val = tanhf(s);
            const unsigned short hi = f2bf(val);
            const unsigned short lo = f2bf(val - bf2f(hi));
            *(unsigned short*)(staging + stg)      = hi;
            *(unsigned short*)(staging + stg + 16) = lo;
        }
        __syncthreads();

        // ---- coalesced 2KB chunk store (128 x 16B, sc1) ----
        {
            char* hw = (layer ? h2base : h1base)
                     + (size_t)((t & sm) * 4 + grp) * 65536 + (size_t)slot * 2048;
            if (tid < 128) {
                const char* src = staging + tid * 16;
                store_h16(hw + tid * 16, *(const u64*)src, *(const u64*)(src + 8));
            }
        }
        asm volatile("s_waitcnt vmcnt(0)" ::: "memory");
        __syncthreads();
        if (tid == 0)
            st_flag((layer ? fB : fA) + (size_t)(grp * 32 + slot) * 16, (unsigned)(t + 1));

        // ---- x prefetch for t+1 (hides under next poll) ----
        if (layer == 0 && t + 1 < TT)
            ld8(xv, x + ((size_t)(b0 + col) * TT + (t + 1)) * II + (w * 32 + kg * 8));
    }

    // ---- FC gate: all 128 L1 flags >= TT, fence, then FC ----
    if (tid < 128) {
        while ((int)ld_flag(fB + (size_t)tid * 16) < TT)
            __builtin_amdgcn_s_sleep(2);
    }
    __syncthreads();
    acquire_fence();

    // FC: block computes out[:, 2*bid .. 2*bid+1]; h2(TT-1) at slot (TT-1)&sm
    float* Wlds = shmem + 2560;
    ((float4*)Wlds)[tid] = ((const float4*)(Wfc + (size_t)(2 * bid) * HH))[tid];
    __syncthreads();

    float p0 = 0.f, p1 = 0.f;
    {
        const int gr   = lane >> 4;
        const int bsub = lane & 15;
        const char* hb = h2base + (size_t)(((TT - 1) & sm) * 4 + gr) * 65536;
        #pragma unroll 4
        for (int k8 = w * 16; k8 < w * 16 + 16; ++k8) {
            const char* p = hb + (size_t)(k8 >> 2) * 2048
                          + (size_t)(bsub + ((k8 & 3) << 4)) * 32;
            bf8 hi = load_h(p), lo = load_h(p + 16);
            const int kb = k8 * 8;
            #pragma unroll
            for (int j = 0; j < 8; ++j) {
                float f = bf2f((unsigned short)hi[j]) + bf2f((unsigned short)lo[j]);
                p0 += f * Wlds[kb + j];
                p1 += f * Wlds[1024 + kb + j];
            }
        }
    }
    __syncthreads();
    shmem[(w * 64 + lane) * 2 + 0] = p0;
    shmem[(w * 64 + lane) * 2 + 1] = p1;
    __syncthreads();
    if (w < 2) {
        float s = bfc[2 * bid + w];
        #pragma unroll
        for (int j = 0; j < 8; ++j) s += shmem[(j * 64 + lane) * 2 + w];
        out[(size_t)lane * OO + 2 * bid + w] = s;
    }
}

extern "C" void kernel_launch(void* const* d_in, const int* in_sizes, int n_in,
                              void* d_out, int out_size, void* d_ws, size_t ws_size,
                              hipStream_t stream) {
    const float* x    = (const float*)d_in[0];
    const float* Wih0 = (const float*)d_in[1];
    const float* Whh0 = (const float*)d_in[2];
    const float* bih0 = (const float*)d_in[3];
    const float* bhh0 = (const float*)d_in[4];
    const float* Wih1 = (const float*)d_in[5];
    const float* Whh1 = (const float*)d_in[6];
    const float* bih1 = (const float*)d_in[7];
    const float* bhh1 = (const float*)d_in[8];
    const float* Wfc  = (const float*)d_in[9];
    const float* bfc  = (const float*)d_in[10];
    float* out = (float*)d_out;
    float* ws  = (float*)d_ws;

    // Ring depth from ws_size (never assume workspace — R1 lesson):
    // depth d needs 4KB + 2*d*4*64KB. 128 -> 67.1MB, 64 -> 33.6MB (proven R15).
    // (R17 showed ws_size < 134MB: no 256 tier.)
    int depth = 32;
    if (ws_size >= (size_t)4096 + (size_t)2 * 128 * 4 * 65536)      depth = 128;
    else if (ws_size >= (size_t)4096 + (size_t)2 * 64 * 4 * 65536)  depth = 64;
    int sm  = depth - 1;
    int fpm = depth / 2 - 1;
    int lag = depth - 12;   // backpressure slack: overwrite-ahead <= lag+8 = depth-4

    // zero both flag arrays every call (replay-safe)
    hipMemsetAsync(d_ws, 0, 4096, stream);

    void* args[] = { (void*)&x,
                     (void*)&Wih0, (void*)&Whh0, (void*)&bih0, (void*)&bhh0,
                     (void*)&Wih1, (void*)&Whh1, (void*)&bih1, (void*)&bhh1,
                     (void*)&Wfc,  (void*)&bfc,  (void*)&out,  (void*)&ws,
                     (void*)&sm,   (void*)&fpm,  (void*)&lag };
    hipLaunchCooperativeKernel((void*)rnn_lag5, dim3(256), dim3(512),
                               args, 0, stream);
}